// Round 24
// baseline (529.110 us; speedup 1.0000x reference)
//
#include <hip/hip_runtime.h>
#include <math.h>

constexpr int NN = 50000;
constexpr int NE = 1600000;
constexpr float LN_EPS = 1e-5f;

constexpr int NBKT  = 8;                       // coarse dst buckets
constexpr int SPAN  = NN / NBKT;               // 6250 nodes per bucket
constexpr int CHUNK = 2048;                    // edges per pass-1 block
constexpr int NB1   = (NE + CHUNK - 1) / CHUNK;  // 782
constexpr int NSB   = (NN + 255) / 256;        // 196 scan blocks
constexpr int PPB   = 8;                       // degree partial blocks per bucket

constexpr float EXM1 = 0.36787944117144233f;   // e^-1
constexpr float EXM4 = 0.018315638888734179f;  // e^-4
constexpr float EXM9 = 1.2340980408667956e-4f; // e^-9

typedef __attribute__((ext_vector_type(8))) short short8;
typedef __attribute__((ext_vector_type(4))) float f32x4;

__device__ __forceinline__ short f2bf(float f)
{
    unsigned u = __builtin_bit_cast(unsigned, f);
    u += 0x7fffu + ((u >> 16) & 1u);          // RNE
    return (short)(u >> 16);
}

// pack two floats as bf16 pair (lo | hi<<16), RNE, single v_perm_b32 combine
__device__ __forceinline__ unsigned pk2bf(float lo, float hi)
{
    unsigned ul = __builtin_bit_cast(unsigned, lo);
    unsigned uh = __builtin_bit_cast(unsigned, hi);
    ul += 0x7fffu + ((ul >> 16) & 1u);
    uh += 0x7fffu + ((uh >> 16) & 1u);
    return __builtin_amdgcn_perm(uh, ul, 0x07060302u);   // [uh.b3 uh.b2 ul.b3 ul.b2]
}

__device__ __forceinline__ float2 bf2x2(unsigned p)
{
    float2 r;
    r.x = __builtin_bit_cast(float, p << 16);          // low ushort
    r.y = __builtin_bit_cast(float, p & 0xffff0000u);  // high ushort
    return r;
}

// ---------------------------------------------------------------- pass 0: bucket histogram only
__global__ __launch_bounds__(256) void csr_hist(const int* __restrict__ col,
                                                int* __restrict__ histo)
{
    __shared__ int hcnt[NBKT * 4];
    const int tid = threadIdx.x;
    const int w = tid >> 6;
    if (tid < NBKT * 4) hcnt[tid] = 0;
    __syncthreads();
    const int e0 = blockIdx.x * CHUNK;
    const int e1 = min(e0 + CHUNK, NE);
    for (int e = e0 + tid; e < e1; e += 256) {
        int c = col[e];
        atomicAdd(&hcnt[((unsigned)c / (unsigned)SPAN) * 4 + w], 1);
    }
    __syncthreads();
    if (tid < NBKT)
        histo[tid * NB1 + blockIdx.x] =
            hcnt[tid * 4] + hcnt[tid * 4 + 1] + hcnt[tid * 4 + 2] + hcnt[tid * 4 + 3];
}

// ---------------------------------------------------------------- scan of 8*NB1 chunk counts
__global__ __launch_bounds__(256) void csr_scan2(int* __restrict__ histo)
{
    constexpr int M = NBKT * NB1;              // 6256
    constexpr int T = (M + 255) / 256;         // 25
    __shared__ int part[256];
    const int t = threadIdx.x;
    int v[T];
    int s = 0;
    #pragma unroll
    for (int j = 0; j < T; ++j) {
        int i = t * T + j;
        v[j] = (i < M) ? histo[i] : 0;
        s += v[j];
    }
    part[t] = s;
    __syncthreads();
    for (int d = 1; d < 256; d <<= 1) {
        int add = (t >= d) ? part[t - d] : 0;
        __syncthreads();
        part[t] += add;
        __syncthreads();
    }
    int run = part[t] - s;
    #pragma unroll
    for (int j = 0; j < T; ++j) {
        int i = t * T + j;
        if (i < M) { histo[i] = run; run += v[j]; }
    }
}

// ---------------------------------------------------------------- pass 1: partition into buckets
__global__ __launch_bounds__(256) void csr_part(const int* __restrict__ ei,
                                                const int* __restrict__ histo,
                                                uint2* __restrict__ staging)
{
    __shared__ int lcur[NBKT];
    const int tid = threadIdx.x;
    if (tid < NBKT) lcur[tid] = histo[tid * NB1 + blockIdx.x];
    __syncthreads();
    const int e0 = blockIdx.x * CHUNK;
    const int e1 = min(e0 + CHUNK, NE);
    for (int e = e0 + tid; e < e1; e += 256) {
        int r = ei[e];
        int c = ei[NE + e];
        int slot = atomicAdd(&lcur[(unsigned)c / (unsigned)SPAN], 1);
        staging[slot] = make_uint2((unsigned)r, (unsigned)c);
    }
}

// ---------------------------------------------------------------- degree: bucket-local LDS histogram
__global__ __launch_bounds__(256) void deg_part(const uint2* __restrict__ staging,
                                                const int* __restrict__ histo,
                                                int* __restrict__ pcnt)
{
    const int b = blockIdx.x >> 3;             // bucket
    const int p = blockIdx.x & 7;              // part
    __shared__ int cnt[SPAN];
    for (int i = threadIdx.x; i < SPAN; i += 256) cnt[i] = 0;
    __syncthreads();
    const int s0 = histo[b * NB1];
    const int s1 = (b + 1 < NBKT) ? histo[(b + 1) * NB1] : NE;
    const int len = s1 - s0;
    const int per = (len + PPB - 1) / PPB;
    const int e0 = s0 + p * per;
    const int e1 = min(e0 + per, s1);
    for (int i = e0 + threadIdx.x; i < e1; i += 256)
        atomicAdd(&cnt[staging[i].y - (unsigned)(b * SPAN)], 1);
    __syncthreads();
    int* dst = pcnt + (b * PPB + p) * SPAN;
    for (int i = threadIdx.x; i < SPAN; i += 256) dst[i] = cnt[i];
}

__global__ __launch_bounds__(256) void deg_reduce(const int* __restrict__ pcnt,
                                                  int* __restrict__ degi)
{
    int n = blockIdx.x * 256 + threadIdx.x;
    if (n >= NN) return;
    int b = n / SPAN, l = n - b * SPAN;
    const int* src = pcnt + b * PPB * SPAN + l;
    int s = 0;
    #pragma unroll
    for (int p = 0; p < PPB; ++p) s += src[p * SPAN];
    degi[n] = s;
}

// ---------------------------------------------------------------- pass 2: bucket-local scatter
template<int PB2>
__global__ __launch_bounds__(256) void csr_scatter(const uint2* __restrict__ staging,
                                                   const int* __restrict__ off,
                                                   int* __restrict__ cur,
                                                   int* __restrict__ rows)
{
    const int b   = blockIdx.x & (NBKT - 1);
    const int blk = blockIdx.x >> 3;
    const int base = off[b * SPAN];
    const int end  = off[(b + 1) * SPAN];
    for (int i = base + blk * 256 + threadIdx.x; i < end; i += PB2 * 256) {
        uint2 e = staging[i];
        int p = off[e.y] + atomicAdd(&cur[e.y], 1);
        rows[p] = (int)e.x;
    }
}

// ---------------------------------------------------------------- dis
__global__ void dis_kernel(const int* __restrict__ degi, float* __restrict__ dis)
{
    int i = blockIdx.x * 256 + threadIdx.x;
    if (i < NN) dis[i] = rsqrtf((float)degi[i] + 1.0f);   // +1 = self loop
}

// ---------------------------------------------------------------- hierarchical degree scan
__global__ __launch_bounds__(256) void scan_p1(const int* __restrict__ deg,
                                               int* __restrict__ off,
                                               int* __restrict__ partials)
{
    __shared__ int sh[256];
    const int t = threadIdx.x;
    const int i = blockIdx.x * 256 + t;
    int v = (i < NN) ? deg[i] : 0;
    sh[t] = v;
    __syncthreads();
    for (int d = 1; d < 256; d <<= 1) {
        int add = (t >= d) ? sh[t - d] : 0;
        __syncthreads();
        sh[t] += add;
        __syncthreads();
    }
    if (i < NN) off[i] = sh[t] - v;            // local exclusive
    if (t == 255) partials[blockIdx.x] = sh[255];
}

__global__ __launch_bounds__(256) void scan_p2(int* __restrict__ partials)
{
    __shared__ int sh[256];
    const int t = threadIdx.x;
    int v = (t < NSB) ? partials[t] : 0;
    sh[t] = v;
    __syncthreads();
    for (int d = 1; d < 256; d <<= 1) {
        int add = (t >= d) ? sh[t - d] : 0;
        __syncthreads();
        sh[t] += add;
        __syncthreads();
    }
    if (t < NSB) partials[t] = sh[t] - v;      // exclusive
    if (t == 255) partials[NSB] = sh[255];     // total
}

__global__ __launch_bounds__(256) void scan_p3(int* __restrict__ off,
                                               const int* __restrict__ partials)
{
    const int i = blockIdx.x * 256 + threadIdx.x;
    if (i < NN) off[i] += partials[blockIdx.x];
    if (i == 0) off[NN] = partials[NSB];
}

// ---------------------------------------------------------------- B-fragment pack
// wtf[((kk*OT + ot)*64 + lane)*8 + j8]:
//   g4 = lane>>4; s = kk*8 + j8; f = g4*(D/4) + s/5; g5 = s%5; o = ot*16 + (lane&15)
__global__ void pack_frag(const float* __restrict__ sw, const float* __restrict__ bw,
                          short* __restrict__ wtf, int D, int OT, int DO, int total)
{
    int idx = blockIdx.x * 256 + threadIdx.x;
    if (idx >= total) return;
    int j8   = idx & 7;
    int lane = (idx >> 3) & 63;
    int rest = idx >> 9;               // kk*OT + ot
    int ot = rest % OT, kk = rest / OT;
    int g4 = lane >> 4;
    int s  = kk * 8 + j8;
    int f  = g4 * (D / 4) + s / 5;
    int g5 = s % 5;
    int o  = ot * 16 + (lane & 15);
    float val = 0.f;
    if (o < DO) val = (g5 < 4) ? sw[o * D * 4 + f * 4 + g5] : bw[o * D + f];
    wtf[idx] = f2bf(val);
}

// ---------------------------------------------------------------- BN scale/shift table
__global__ void bn_id(float2* __restrict__ bnp)
{
    bnp[threadIdx.x] = make_float2(1.0f, 0.0f);    // identity section (x)
}

__global__ void bn_final(const float* __restrict__ stats, const float* __restrict__ g,
                         const float* __restrict__ b, float2* __restrict__ dst)
{
    int c = threadIdx.x;                            // 128
    float mu  = stats[c] * (1.0f / NN);
    float var = stats[c + 128] * (1.0f / NN) - mu * mu;
    float rs  = rsqrtf(var + LN_EPS);
    float sc  = rs * g[c];
    dst[c] = make_float2(sc, b[c] - mu * sc);
}

// ---------------------------------------------------------------- RBF basis via 2-exp identity
__device__ __forceinline__ void rbf4(float hn, float* bas)
{
    float T  = fmaf(hn, 0.75f, 1.5f);
    float E0 = __expf(-T * T);
    float W  = __expf(T + T);
    float W2 = W * W;
    bas[0] = E0;
    bas[1] = E0 * (W * EXM1);
    bas[2] = E0 * (W2 * EXM4);
    bas[3] = E0 * ((W2 * W) * EXM9);
}

// ---------------------------------------------------------------- FastKAN D=128, register-direct
// 256 threads = 4 independent waves, 16 nodes/wave, NO LDS / NO syncthreads.
template<int DO, int OT, int KKC, bool BN>
__global__ __launch_bounds__(256, 4) void fkan_rd(
    const float* __restrict__ s0, const float2* __restrict__ bnp,
    const float* __restrict__ ln_g, const float* __restrict__ ln_b,
    const short* __restrict__ wtf, const float* __restrict__ sb, const float* __restrict__ bb,
    short* __restrict__ out)
{
    const int tid  = threadIdx.x;
    const int wv   = tid >> 6, lane = tid & 63;
    const int m    = lane & 15, q = lane >> 4;
    const int gnode = blockIdx.x * 64 + wv * 16 + m;
    const int snode = (gnode < NN) ? gnode : (NN - 1);

    // ---- load 32 features (quadrant q) into registers + LN stats
    float4 v[8];
    float sum = 0.f, sq = 0.f;
    #pragma unroll
    for (int i = 0; i < 8; ++i) {
        int f = q * 32 + i * 4;
        float4 t = *(const float4*)&s0[snode * 128 + f];
        if constexpr (BN) {
            float4 ba = *(const float4*)&bnp[f];       // sc0,sh0,sc1,sh1
            float4 bc = *(const float4*)&bnp[f + 2];   // sc2,sh2,sc3,sh3
            t.x = fmaf(t.x, ba.x, ba.y);
            t.y = fmaf(t.y, ba.z, ba.w);
            t.z = fmaf(t.z, bc.x, bc.y);
            t.w = fmaf(t.w, bc.z, bc.w);
        }
        v[i] = t;
        sum += (t.x + t.y) + (t.z + t.w);
        sq  += (t.x * t.x + t.y * t.y) + (t.z * t.z + t.w * t.w);
    }
    sum += __shfl_xor(sum, 16); sum += __shfl_xor(sum, 32);
    sq  += __shfl_xor(sq, 16);  sq  += __shfl_xor(sq, 32);
    const float mu   = sum * (1.0f / 128.0f);
    const float rstd = rsqrtf(sq * (1.0f / 128.0f) - mu * mu + LN_EPS);

    f32x4 acc[OT];
    #pragma unroll
    for (int ot = 0; ot < OT; ++ot) acc[ot] = f32x4{0.f, 0.f, 0.f, 0.f};

    union AU { unsigned u[4]; short8 s; };

    #pragma unroll
    for (int pl = 0; pl < KKC / 5; ++pl) {         // 4 periods of 8 features
        float bas[8][4], slv[8];
        {
            float4 lg0 = *(const float4*)&ln_g[q * 32 + pl * 8];
            float4 lg1 = *(const float4*)&ln_g[q * 32 + pl * 8 + 4];
            float4 lb0 = *(const float4*)&ln_b[q * 32 + pl * 8];
            float4 lb1 = *(const float4*)&ln_b[q * 32 + pl * 8 + 4];
            float4 va = v[pl * 2], vb = v[pl * 2 + 1];
            float hn[8];
            hn[0] = (va.x - mu) * rstd * lg0.x + lb0.x;
            hn[1] = (va.y - mu) * rstd * lg0.y + lb0.y;
            hn[2] = (va.z - mu) * rstd * lg0.z + lb0.z;
            hn[3] = (va.w - mu) * rstd * lg0.w + lb0.w;
            hn[4] = (vb.x - mu) * rstd * lg1.x + lb1.x;
            hn[5] = (vb.y - mu) * rstd * lg1.y + lb1.y;
            hn[6] = (vb.z - mu) * rstd * lg1.z + lb1.z;
            hn[7] = (vb.w - mu) * rstd * lg1.w + lb1.w;
            #pragma unroll
            for (int fl = 0; fl < 8; ++fl) rbf4(hn[fl], bas[fl]);
            slv[0] = va.x / (1.0f + __expf(-va.x));
            slv[1] = va.y / (1.0f + __expf(-va.y));
            slv[2] = va.z / (1.0f + __expf(-va.z));
            slv[3] = va.w / (1.0f + __expf(-va.w));
            slv[4] = vb.x / (1.0f + __expf(-vb.x));
            slv[5] = vb.y / (1.0f + __expf(-vb.y));
            slv[6] = vb.z / (1.0f + __expf(-vb.z));
            slv[7] = vb.w / (1.0f + __expf(-vb.w));
        }
        const short* bp = wtf + (pl * 5) * OT * 512 + lane * 8;
        #pragma unroll
        for (int c = 0; c < 5; ++c) {
            AU a;
            #pragma unroll
            for (int i = 0; i < 4; ++i) {
                int s0i = c * 8 + 2 * i, s1i = s0i + 1;   // compile-time slot ids
                float vlo = (s0i % 5 == 4) ? slv[s0i / 5] : bas[s0i / 5][s0i % 5];
                float vhi = (s1i % 5 == 4) ? slv[s1i / 5] : bas[s1i / 5][s1i % 5];
                a.u[i] = pk2bf(vlo, vhi);
            }
            #pragma unroll
            for (int ot = 0; ot < OT; ++ot) {
                short8 b = *(const short8*)(bp + (c * OT + ot) * 512);
                acc[ot] = __builtin_amdgcn_mfma_f32_16x16x32_bf16(a.s, b, acc[ot], 0, 0, 0);
            }
        }
    }

    // ---- epilogue: bf16 write, C/D: col=lane&15, row=(lane>>4)*4+reg
    const int nrow0 = blockIdx.x * 64 + wv * 16 + q * 4;
    #pragma unroll
    for (int ot = 0; ot < OT; ++ot) {
        int o = ot * 16 + m;
        if (o < DO) {
            float cb = sb[o] + bb[o];
            #pragma unroll
            for (int r = 0; r < 4; ++r) {
                int nr = nrow0 + r;
                if (nr < NN) out[nr * DO + o] = f2bf(acc[ot][r] + cb);
            }
        }
    }
}

// ---------------------------------------------------------------- FastKAN layer (LDS-staged, conv2)
template<int D, int DO, int OT, int KKC, int NODES, int WPE, bool RAWLDS, bool BN>
__global__ __launch_bounds__(NODES * 4, WPE) void fkan_reg(
    const float* __restrict__ s0, const float* __restrict__ s1, const float* __restrict__ s2,
    const float2* __restrict__ bnp,
    const float* __restrict__ ln_g, const float* __restrict__ ln_b,
    const short* __restrict__ wtf, const float* __restrict__ sb, const float* __restrict__ bb,
    short* __restrict__ out)
{
    constexpr int BW   = D / 4;        // features per g4-block (per thread)
    constexpr int GBS  = BW + 1;       // g4-block stride (u32)
    constexpr int RS   = 4 * GBS + 1;  // node row stride (u32)
    constexpr int PPC  = KKC / 5;      // periods (8 feat each)
    constexpr int NV   = RAWLDS ? 1 : (BW / 4);
    __shared__ unsigned pkL[NODES * RS];

    const int tid = threadIdx.x;
    const int anode = tid >> 2, q = tid & 3;
    const int gnode = blockIdx.x * NODES + anode;
    const int snode = (gnode < NN) ? gnode : (NN - 1);
    unsigned* prow = &pkL[anode * RS + q * GBS];

    float mu, rstd;
    float4 va[NV];
    {
        float sum = 0.f, sq = 0.f;
        #pragma unroll
        for (int i4 = 0; i4 < BW / 4; ++i4) {
            int f = q * BW + i4 * 4;
            const float* src = (D == 128) ? s0 : ((f < 128) ? s0 : (f < 256) ? s1 : s2);
            float4 v = *(const float4*)&src[snode * 128 + (f & 127)];
            if constexpr (BN) {
                float4 ba = *(const float4*)&bnp[f];       // sc0,sh0,sc1,sh1
                float4 bc = *(const float4*)&bnp[f + 2];   // sc2,sh2,sc3,sh3
                v.x = fmaf(v.x, ba.x, ba.y);
                v.y = fmaf(v.y, ba.z, ba.w);
                v.z = fmaf(v.z, bc.x, bc.y);
                v.w = fmaf(v.w, bc.z, bc.w);
            }
            if constexpr (RAWLDS) {
                prow[i4 * 4 + 0] = __builtin_bit_cast(unsigned, v.x);
                prow[i4 * 4 + 1] = __builtin_bit_cast(unsigned, v.y);
                prow[i4 * 4 + 2] = __builtin_bit_cast(unsigned, v.z);
                prow[i4 * 4 + 3] = __builtin_bit_cast(unsigned, v.w);
            } else {
                va[i4] = v;
            }
            sum += (v.x + v.y) + (v.z + v.w);
            sq  += (v.x * v.x + v.y * v.y) + (v.z * v.z + v.w * v.w);
        }
        sum += __shfl_xor(sum, 1); sum += __shfl_xor(sum, 2);
        sq  += __shfl_xor(sq, 1);  sq  += __shfl_xor(sq, 2);
        mu   = sum * (1.0f / D);
        rstd = rsqrtf(sq * (1.0f / D) - mu * mu + LN_EPS);
    }

    // ---- phase A2: LN + silu, pk into LDS (in place for RAWLDS), 4 features/iter
    #pragma unroll
    for (int i4 = 0; i4 < BW / 4; ++i4) {
        int f = q * BW + i4 * 4;
        float4 v;
        if constexpr (RAWLDS) {
            v.x = __builtin_bit_cast(float, prow[i4 * 4 + 0]);
            v.y = __builtin_bit_cast(float, prow[i4 * 4 + 1]);
            v.z = __builtin_bit_cast(float, prow[i4 * 4 + 2]);
            v.w = __builtin_bit_cast(float, prow[i4 * 4 + 3]);
        } else {
            v = va[i4];
        }
        float4 lg = *(const float4*)&ln_g[f];
        float4 lb = *(const float4*)&ln_b[f];
        float hn[4], sl[4];
        hn[0] = (v.x - mu) * rstd * lg.x + lb.x;
        hn[1] = (v.y - mu) * rstd * lg.y + lb.y;
        hn[2] = (v.z - mu) * rstd * lg.z + lb.z;
        hn[3] = (v.w - mu) * rstd * lg.w + lb.w;
        sl[0] = v.x / (1.0f + __expf(-v.x));
        sl[1] = v.y / (1.0f + __expf(-v.y));
        sl[2] = v.z / (1.0f + __expf(-v.z));
        sl[3] = v.w / (1.0f + __expf(-v.w));
        #pragma unroll
        for (int k = 0; k < 4; ++k)
            prow[i4 * 4 + k] = pk2bf(sl[k], hn[k]);    // lo=silu, hi=hn
    }
    __syncthreads();

    // ---- phase 2: register-A MFMA (8 LDS reads/period, 2-exp RBF, perm pack)
    const int wv = tid >> 6, lane = tid & 63;
    const int m = lane & 15, g4 = lane >> 4;
    const unsigned* pkb = &pkL[(wv * 16 + m) * RS + g4 * GBS];

    f32x4 acc[OT];
    #pragma unroll
    for (int ot = 0; ot < OT; ++ot) acc[ot] = f32x4{0.f, 0.f, 0.f, 0.f};

    union AU { unsigned u[4]; short8 s; };

    for (int pl = 0; pl < PPC; ++pl) {             // 5 kk = 40 slots = 8 features
        const unsigned* pp = pkb + pl * 8;
        float bas[8][4], slv[8];
        #pragma unroll
        for (int fl = 0; fl < 8; ++fl) {
            unsigned pv = pp[fl];
            float hn = __builtin_bit_cast(float, pv & 0xffff0000u);
            slv[fl]  = __builtin_bit_cast(float, pv << 16);
            rbf4(hn, bas[fl]);
        }
        const short* bp = wtf + (pl * 5) * OT * 512 + lane * 8;
        #pragma unroll
        for (int c = 0; c < 5; ++c) {
            AU a;
            #pragma unroll
            for (int i = 0; i < 4; ++i) {
                int s0i = c * 8 + 2 * i, s1i = s0i + 1;   // compile-time slot ids
                float vlo = (s0i % 5 == 4) ? slv[s0i / 5] : bas[s0i / 5][s0i % 5];
                float vhi = (s1i % 5 == 4) ? slv[s1i / 5] : bas[s1i / 5][s1i % 5];
                a.u[i] = pk2bf(vlo, vhi);
            }
            #pragma unroll
            for (int ot = 0; ot < OT; ++ot) {
                short8 b = *(const short8*)(bp + (c * OT + ot) * 512);
                acc[ot] = __builtin_amdgcn_mfma_f32_16x16x32_bf16(a.s, b, acc[ot], 0, 0, 0);
            }
        }
    }

    // ---- epilogue: bf16 write, C/D: col=lane&15, row=(lane>>4)*4+reg
    const int nrow0 = blockIdx.x * NODES + wv * 16 + g4 * 4;
    #pragma unroll
    for (int ot = 0; ot < OT; ++ot) {
        int o = ot * 16 + m;
        if (o < DO) {
            float cb = sb[o] + bb[o];
            #pragma unroll
            for (int r = 0; r < 4; ++r) {
                int nr = nrow0 + r;
                if (nr < NN) out[nr * DO + o] = f2bf(acc[ot][r] + cb);
            }
        }
    }
}

// ---------------------------------------------------------------- CSR gather (bf16 rows, 2-row MLP)
template<int DO>
__global__ __launch_bounds__(64) void agg_gather_bf16(
    const int* __restrict__ off, const int* __restrict__ rows,
    const float* __restrict__ dis, const short* __restrict__ hwb,
    const float* __restrict__ bias, float* __restrict__ out)
{
    constexpr int ACT = DO / 2;        // active compute lanes
    const int n   = blockIdx.x;
    const int tid = threadIdx.x;
    __shared__ int   srow[64];
    __shared__ float swgt[64];

    const int e0 = off[n], e1 = off[n + 1];
    const float dn = dis[n];
    float ax = 0.f, ay = 0.f, bx = 0.f, by = 0.f;
    if (tid < ACT) {
        unsigned p = *(const unsigned*)&hwb[n * DO + 2 * tid];
        float2 v = bf2x2(p);
        ax = dn * dn * v.x + bias[2 * tid];
        ay = dn * dn * v.y + bias[2 * tid + 1];
    }

    for (int t0 = e0; t0 < e1; t0 += 64) {
        const int nt = min(64, e1 - t0);
        if (tid < nt) {
            int r = rows[t0 + tid];
            srow[tid] = r;
            swgt[tid] = dn * dis[r];
        }
        __syncthreads();
        if (tid < ACT) {
            int j = 0;
            for (; j + 2 <= nt; j += 2) {      // two rows in flight per iter
                unsigned p0 = *(const unsigned*)&hwb[srow[j]     * DO + 2 * tid];
                unsigned p1 = *(const unsigned*)&hwb[srow[j + 1] * DO + 2 * tid];
                float w0 = swgt[j], w1 = swgt[j + 1];
                float2 v0 = bf2x2(p0), v1 = bf2x2(p1);
                ax += w0 * v0.x; ay += w0 * v0.y;
                bx += w1 * v1.x; by += w1 * v1.y;
            }
            if (j < nt) {
                unsigned p = *(const unsigned*)&hwb[srow[j] * DO + 2 * tid];
                float2 v = bf2x2(p);
                float w = swgt[j];
                ax += w * v.x; ay += w * v.y;
            }
        }
        __syncthreads();
    }
    if (tid < ACT) {
        out[n * DO + 2 * tid]     = ax + bx;
        out[n * DO + 2 * tid + 1] = ay + by;
    }
}

// ---------------------------------------------------------------- batchnorm stats
__global__ void bn_stats(const float* __restrict__ h, float* __restrict__ stats)
{
    __shared__ float s1[256], s2[256];
    int c = threadIdx.x & 127;
    int half = threadIdx.x >> 7;
    float sum = 0.f, sq = 0.f;
    for (int n = blockIdx.x * 2 + half; n < NN; n += 512) {
        float v = h[n * 128 + c];
        sum += v; sq += v * v;
    }
    s1[threadIdx.x] = sum; s2[threadIdx.x] = sq;
    __syncthreads();
    if (half == 0) {
        s1[c] += s1[c + 128]; s2[c] += s2[c + 128];
        atomicAdd(&stats[c],        s1[c]);
        atomicAdd(&stats[c + 128],  s2[c]);
    }
}

// ---------------------------------------------------------------- launcher
extern "C" void kernel_launch(void* const* d_in, const int* in_sizes, int n_in,
                              void* d_out, int out_size, void* d_ws, size_t ws_size,
                              hipStream_t stream)
{
    auto F = [&](int i) { return (const float*)d_in[i]; };
    const float* x  = F(0);
    const int*   ei = (const int*)d_in[1];
    const float* bn_g = F(23);
    const float* bn_b = F(24);
    // per-conv params: base = 2 + 7*i : ln_g, ln_b, sw, sb, bw, bb, bias

    // ---- workspace layout
    short*  wtf0 = (short*)d_ws;                // 81920 shorts
    short*  wtf1 = wtf0 + 81920;                // 81920
    short*  wtf2 = wtf1 + 81920;                // 92160
    short*  hwb  = wtf2 + 92160;                // NN*128 bf16 (NN*40 for conv2)
    float*  dis  = (float*)(hwb + 6400000);     // NN
    float2* bnp  = (float2*)(dis + 50000);      // 384: [id | conv0-bn | conv1-bn]
    float*  h1   = (float*)(bnp + 384);         // NN*128 (raw agg)
    float*  h2   = h1 + 6400000;
    float*  stats = h2 + 6400000;               // 256
    int*    degi = (int*)(stats + 256);         // NN
    int*    off  = degi + 50000;                // NN+1
    int*    cur  = off + 50001;                 // NN
    int*    rows = cur + 50000;                 // NE
    int*    histo = rows + NE;                  // 8*NB1 = 6256
    int*    partials = histo + NBKT * NB1;      // NSB+1 = 197
    int*    pcnt = partials + NSB + 1;          // 8*8*6250 = 400000
    uint2*  staging = (uint2*)h1;               // 12.8 MB, dead until conv0 output
    float*  outf = (float*)d_out;

    // ---- CSR build: hist -> scan2 -> part -> degree (LDS hist) -> scans -> scatter
    (void)hipMemsetAsync(cur, 0, 50000 * sizeof(int), stream);
    csr_hist<<<NB1, 256, 0, stream>>>(ei + NE, histo);
    csr_scan2<<<1, 256, 0, stream>>>(histo);
    csr_part<<<NB1, 256, 0, stream>>>(ei, histo, staging);
    deg_part<<<NBKT * PPB, 256, 0, stream>>>(staging, histo, pcnt);
    deg_reduce<<<NSB, 256, 0, stream>>>(pcnt, degi);
    dis_kernel<<<(NN + 255) / 256, 256, 0, stream>>>(degi, dis);
    scan_p1<<<NSB, 256, 0, stream>>>(degi, off, partials);
    scan_p2<<<1, 256, 0, stream>>>(partials);
    scan_p3<<<NSB, 256, 0, stream>>>(off, partials);
    csr_scatter<128><<<128 * NBKT, 256, 0, stream>>>(staging, off, cur, rows);

    // ---- pack B fragments (bf16), BN identity section
    pack_frag<<<(81920 + 255) / 256, 256, 0, stream>>>(F(4),  F(6),  wtf0, 128, 8, 128, 81920);
    pack_frag<<<(81920 + 255) / 256, 256, 0, stream>>>(F(11), F(13), wtf1, 128, 8, 128, 81920);
    pack_frag<<<(92160 + 255) / 256, 256, 0, stream>>>(F(18), F(20), wtf2, 384, 3, 40,  92160);
    bn_id<<<1, 128, 0, stream>>>(bnp);

    const int gridN64 = (NN + 63) / 64;         // 782
    const int gridN16 = (NN + 15) / 16;         // 3125

    // ---- conv0: x -> h1 (register-direct fkan, no LDS)
    fkan_rd<128, 8, 20, false><<<gridN64, 256, 0, stream>>>(x,
        nullptr, F(2), F(3), wtf0, F(5), F(7), hwb);
    agg_gather_bf16<128><<<NN, 64, 0, stream>>>(off, rows, dis, hwb, F(8), h1);
    (void)hipMemsetAsync(stats, 0, 256 * sizeof(float), stream);
    bn_stats<<<256, 256, 0, stream>>>(h1, stats);
    bn_final<<<1, 128, 0, stream>>>(stats, bn_g, bn_b, bnp + 128);

    // ---- conv1: h1 -> h2 (register-direct fkan, BN fused)
    fkan_rd<128, 8, 20, true><<<gridN64, 256, 0, stream>>>(h1,
        bnp + 128, F(9), F(10), wtf1, F(12), F(14), hwb);
    agg_gather_bf16<128><<<NN, 64, 0, stream>>>(off, rows, dis, hwb, F(15), h2);
    (void)hipMemsetAsync(stats, 0, 256 * sizeof(float), stream);
    bn_stats<<<256, 256, 0, stream>>>(h2, stats);
    bn_final<<<1, 128, 0, stream>>>(stats, bn_g, bn_b, bnp + 256);

    // ---- conv2: [x|h1|h2] -> d_out (raw-LDS staging, 16-node single-wave blocks)
    fkan_reg<384, 40, 3, 60, 16, 2, true, true><<<gridN16, 64, 0, stream>>>(x, h1, h2,
        bnp, F(16), F(17), wtf2, F(19), F(21), hwb);
    agg_gather_bf16<40><<<NN, 64, 0, stream>>>(off, rows, dis, hwb, F(22), outf);
}

// Round 25
// 498.150 us; speedup vs baseline: 1.0621x; 1.0621x over previous
//
#include <hip/hip_runtime.h>
#include <math.h>

constexpr int NN = 50000;
constexpr int NE = 1600000;
constexpr float LN_EPS = 1e-5f;

constexpr int NBKT  = 8;                       // coarse dst buckets
constexpr int SPAN  = NN / NBKT;               // 6250 nodes per bucket
constexpr int CHUNK = 2048;                    // edges per pass-1 block
constexpr int NB1   = (NE + CHUNK - 1) / CHUNK;  // 782
constexpr int NSB   = (NN + 255) / 256;        // 196 scan blocks
constexpr int PPB   = 8;                       // degree partial blocks per bucket

constexpr float EXM1 = 0.36787944117144233f;   // e^-1
constexpr float EXM4 = 0.018315638888734179f;  // e^-4
constexpr float EXM9 = 1.2340980408667956e-4f; // e^-9

typedef __attribute__((ext_vector_type(8))) short short8;
typedef __attribute__((ext_vector_type(4))) float f32x4;

__device__ __forceinline__ short f2bf(float f)
{
    unsigned u = __builtin_bit_cast(unsigned, f);
    u += 0x7fffu + ((u >> 16) & 1u);          // RNE
    return (short)(u >> 16);
}

// pack two floats as bf16 pair (lo | hi<<16), RNE, single v_perm_b32 combine
__device__ __forceinline__ unsigned pk2bf(float lo, float hi)
{
    unsigned ul = __builtin_bit_cast(unsigned, lo);
    unsigned uh = __builtin_bit_cast(unsigned, hi);
    ul += 0x7fffu + ((ul >> 16) & 1u);
    uh += 0x7fffu + ((uh >> 16) & 1u);
    return __builtin_amdgcn_perm(uh, ul, 0x07060302u);   // [uh.b3 uh.b2 ul.b3 ul.b2]
}

__device__ __forceinline__ float2 bf2x2(unsigned p)
{
    float2 r;
    r.x = __builtin_bit_cast(float, p << 16);          // low ushort
    r.y = __builtin_bit_cast(float, p & 0xffff0000u);  // high ushort
    return r;
}

// ---------------------------------------------------------------- pass 0: bucket histogram only
__global__ __launch_bounds__(256) void csr_hist(const int* __restrict__ col,
                                                int* __restrict__ histo)
{
    __shared__ int hcnt[NBKT * 4];
    const int tid = threadIdx.x;
    const int w = tid >> 6;
    if (tid < NBKT * 4) hcnt[tid] = 0;
    __syncthreads();
    const int e0 = blockIdx.x * CHUNK;
    const int e1 = min(e0 + CHUNK, NE);
    for (int e = e0 + tid; e < e1; e += 256) {
        int c = col[e];
        atomicAdd(&hcnt[((unsigned)c / (unsigned)SPAN) * 4 + w], 1);
    }
    __syncthreads();
    if (tid < NBKT)
        histo[tid * NB1 + blockIdx.x] =
            hcnt[tid * 4] + hcnt[tid * 4 + 1] + hcnt[tid * 4 + 2] + hcnt[tid * 4 + 3];
}

// ---------------------------------------------------------------- scan of 8*NB1 chunk counts
__global__ __launch_bounds__(256) void csr_scan2(int* __restrict__ histo)
{
    constexpr int M = NBKT * NB1;              // 6256
    constexpr int T = (M + 255) / 256;         // 25
    __shared__ int part[256];
    const int t = threadIdx.x;
    int v[T];
    int s = 0;
    #pragma unroll
    for (int j = 0; j < T; ++j) {
        int i = t * T + j;
        v[j] = (i < M) ? histo[i] : 0;
        s += v[j];
    }
    part[t] = s;
    __syncthreads();
    for (int d = 1; d < 256; d <<= 1) {
        int add = (t >= d) ? part[t - d] : 0;
        __syncthreads();
        part[t] += add;
        __syncthreads();
    }
    int run = part[t] - s;
    #pragma unroll
    for (int j = 0; j < T; ++j) {
        int i = t * T + j;
        if (i < M) { histo[i] = run; run += v[j]; }
    }
}

// ---------------------------------------------------------------- pass 1: partition into buckets
__global__ __launch_bounds__(256) void csr_part(const int* __restrict__ ei,
                                                const int* __restrict__ histo,
                                                uint2* __restrict__ staging)
{
    __shared__ int lcur[NBKT];
    const int tid = threadIdx.x;
    if (tid < NBKT) lcur[tid] = histo[tid * NB1 + blockIdx.x];
    __syncthreads();
    const int e0 = blockIdx.x * CHUNK;
    const int e1 = min(e0 + CHUNK, NE);
    for (int e = e0 + tid; e < e1; e += 256) {
        int r = ei[e];
        int c = ei[NE + e];
        int slot = atomicAdd(&lcur[(unsigned)c / (unsigned)SPAN], 1);
        staging[slot] = make_uint2((unsigned)r, (unsigned)c);
    }
}

// ---------------------------------------------------------------- degree: bucket-local LDS histogram
__global__ __launch_bounds__(256) void deg_part(const uint2* __restrict__ staging,
                                                const int* __restrict__ histo,
                                                int* __restrict__ pcnt)
{
    const int b = blockIdx.x >> 3;             // bucket
    const int p = blockIdx.x & 7;              // part
    __shared__ int cnt[SPAN];
    for (int i = threadIdx.x; i < SPAN; i += 256) cnt[i] = 0;
    __syncthreads();
    const int s0 = histo[b * NB1];
    const int s1 = (b + 1 < NBKT) ? histo[(b + 1) * NB1] : NE;
    const int len = s1 - s0;
    const int per = (len + PPB - 1) / PPB;
    const int e0 = s0 + p * per;
    const int e1 = min(e0 + per, s1);
    for (int i = e0 + threadIdx.x; i < e1; i += 256)
        atomicAdd(&cnt[staging[i].y - (unsigned)(b * SPAN)], 1);
    __syncthreads();
    int* dst = pcnt + (b * PPB + p) * SPAN;
    for (int i = threadIdx.x; i < SPAN; i += 256) dst[i] = cnt[i];
}

__global__ __launch_bounds__(256) void deg_reduce(const int* __restrict__ pcnt,
                                                  int* __restrict__ degi)
{
    int n = blockIdx.x * 256 + threadIdx.x;
    if (n >= NN) return;
    int b = n / SPAN, l = n - b * SPAN;
    const int* src = pcnt + b * PPB * SPAN + l;
    int s = 0;
    #pragma unroll
    for (int p = 0; p < PPB; ++p) s += src[p * SPAN];
    degi[n] = s;
}

// ---------------------------------------------------------------- pass 2: bucket-local scatter
template<int PB2>
__global__ __launch_bounds__(256) void csr_scatter(const uint2* __restrict__ staging,
                                                   const int* __restrict__ off,
                                                   int* __restrict__ cur,
                                                   int* __restrict__ rows)
{
    const int b   = blockIdx.x & (NBKT - 1);
    const int blk = blockIdx.x >> 3;
    const int base = off[b * SPAN];
    const int end  = off[(b + 1) * SPAN];
    for (int i = base + blk * 256 + threadIdx.x; i < end; i += PB2 * 256) {
        uint2 e = staging[i];
        int p = off[e.y] + atomicAdd(&cur[e.y], 1);
        rows[p] = (int)e.x;
    }
}

// ---------------------------------------------------------------- dis
__global__ void dis_kernel(const int* __restrict__ degi, float* __restrict__ dis)
{
    int i = blockIdx.x * 256 + threadIdx.x;
    if (i < NN) dis[i] = rsqrtf((float)degi[i] + 1.0f);   // +1 = self loop
}

// ---------------------------------------------------------------- hierarchical degree scan
__global__ __launch_bounds__(256) void scan_p1(const int* __restrict__ deg,
                                               int* __restrict__ off,
                                               int* __restrict__ partials)
{
    __shared__ int sh[256];
    const int t = threadIdx.x;
    const int i = blockIdx.x * 256 + t;
    int v = (i < NN) ? deg[i] : 0;
    sh[t] = v;
    __syncthreads();
    for (int d = 1; d < 256; d <<= 1) {
        int add = (t >= d) ? sh[t - d] : 0;
        __syncthreads();
        sh[t] += add;
        __syncthreads();
    }
    if (i < NN) off[i] = sh[t] - v;            // local exclusive
    if (t == 255) partials[blockIdx.x] = sh[255];
}

__global__ __launch_bounds__(256) void scan_p2(int* __restrict__ partials)
{
    __shared__ int sh[256];
    const int t = threadIdx.x;
    int v = (t < NSB) ? partials[t] : 0;
    sh[t] = v;
    __syncthreads();
    for (int d = 1; d < 256; d <<= 1) {
        int add = (t >= d) ? sh[t - d] : 0;
        __syncthreads();
        sh[t] += add;
        __syncthreads();
    }
    if (t < NSB) partials[t] = sh[t] - v;      // exclusive
    if (t == 255) partials[NSB] = sh[255];     // total
}

__global__ __launch_bounds__(256) void scan_p3(int* __restrict__ off,
                                               const int* __restrict__ partials)
{
    const int i = blockIdx.x * 256 + threadIdx.x;
    if (i < NN) off[i] += partials[blockIdx.x];
    if (i == 0) off[NN] = partials[NSB];
}

// ---------------------------------------------------------------- B-fragment pack
// wtf[((kk*OT + ot)*64 + lane)*8 + j8]:
//   g4 = lane>>4; s = kk*8 + j8; f = g4*(D/4) + s/5; g5 = s%5; o = ot*16 + (lane&15)
__global__ void pack_frag(const float* __restrict__ sw, const float* __restrict__ bw,
                          short* __restrict__ wtf, int D, int OT, int DO, int total)
{
    int idx = blockIdx.x * 256 + threadIdx.x;
    if (idx >= total) return;
    int j8   = idx & 7;
    int lane = (idx >> 3) & 63;
    int rest = idx >> 9;               // kk*OT + ot
    int ot = rest % OT, kk = rest / OT;
    int g4 = lane >> 4;
    int s  = kk * 8 + j8;
    int f  = g4 * (D / 4) + s / 5;
    int g5 = s % 5;
    int o  = ot * 16 + (lane & 15);
    float val = 0.f;
    if (o < DO) val = (g5 < 4) ? sw[o * D * 4 + f * 4 + g5] : bw[o * D + f];
    wtf[idx] = f2bf(val);
}

// ---------------------------------------------------------------- BN scale/shift table
__global__ void bn_id(float2* __restrict__ bnp)
{
    bnp[threadIdx.x] = make_float2(1.0f, 0.0f);    // identity section (x)
}

__global__ void bn_final(const float* __restrict__ stats, const float* __restrict__ g,
                         const float* __restrict__ b, float2* __restrict__ dst)
{
    int c = threadIdx.x;                            // 128
    float mu  = stats[c] * (1.0f / NN);
    float var = stats[c + 128] * (1.0f / NN) - mu * mu;
    float rs  = rsqrtf(var + LN_EPS);
    float sc  = rs * g[c];
    dst[c] = make_float2(sc, b[c] - mu * sc);
}

// ---------------------------------------------------------------- RBF basis via 2-exp identity
__device__ __forceinline__ void rbf4(float hn, float* bas)
{
    float T  = fmaf(hn, 0.75f, 1.5f);
    float E0 = __expf(-T * T);
    float W  = __expf(T + T);
    float W2 = W * W;
    bas[0] = E0;
    bas[1] = E0 * (W * EXM1);
    bas[2] = E0 * (W2 * EXM4);
    bas[3] = E0 * ((W2 * W) * EXM9);
}

// ---------------------------------------------------------------- FastKAN D=128, register-direct
// 256 threads = 4 independent waves, 16 nodes/wave, NO LDS / NO syncthreads.
template<int DO, int OT, int KKC, bool BN>
__global__ __launch_bounds__(256, 4) void fkan_rd(
    const float* __restrict__ s0, const float2* __restrict__ bnp,
    const float* __restrict__ ln_g, const float* __restrict__ ln_b,
    const short* __restrict__ wtf, const float* __restrict__ sb, const float* __restrict__ bb,
    short* __restrict__ out)
{
    const int tid  = threadIdx.x;
    const int wv   = tid >> 6, lane = tid & 63;
    const int m    = lane & 15, q = lane >> 4;
    const int gnode = blockIdx.x * 64 + wv * 16 + m;
    const int snode = (gnode < NN) ? gnode : (NN - 1);

    // ---- load 32 features (quadrant q) into registers + LN stats
    float4 v[8];
    float sum = 0.f, sq = 0.f;
    #pragma unroll
    for (int i = 0; i < 8; ++i) {
        int f = q * 32 + i * 4;
        float4 t = *(const float4*)&s0[snode * 128 + f];
        if constexpr (BN) {
            float4 ba = *(const float4*)&bnp[f];       // sc0,sh0,sc1,sh1
            float4 bc = *(const float4*)&bnp[f + 2];   // sc2,sh2,sc3,sh3
            t.x = fmaf(t.x, ba.x, ba.y);
            t.y = fmaf(t.y, ba.z, ba.w);
            t.z = fmaf(t.z, bc.x, bc.y);
            t.w = fmaf(t.w, bc.z, bc.w);
        }
        v[i] = t;
        sum += (t.x + t.y) + (t.z + t.w);
        sq  += (t.x * t.x + t.y * t.y) + (t.z * t.z + t.w * t.w);
    }
    sum += __shfl_xor(sum, 16); sum += __shfl_xor(sum, 32);
    sq  += __shfl_xor(sq, 16);  sq  += __shfl_xor(sq, 32);
    const float mu   = sum * (1.0f / 128.0f);
    const float rstd = rsqrtf(sq * (1.0f / 128.0f) - mu * mu + LN_EPS);

    f32x4 acc[OT];
    #pragma unroll
    for (int ot = 0; ot < OT; ++ot) acc[ot] = f32x4{0.f, 0.f, 0.f, 0.f};

    union AU { unsigned u[4]; short8 s; };

    #pragma unroll
    for (int pl = 0; pl < KKC / 5; ++pl) {         // 4 periods of 8 features
        float bas[8][4], slv[8];
        {
            float4 lg0 = *(const float4*)&ln_g[q * 32 + pl * 8];
            float4 lg1 = *(const float4*)&ln_g[q * 32 + pl * 8 + 4];
            float4 lb0 = *(const float4*)&ln_b[q * 32 + pl * 8];
            float4 lb1 = *(const float4*)&ln_b[q * 32 + pl * 8 + 4];
            float4 va = v[pl * 2], vb = v[pl * 2 + 1];
            float hn[8];
            hn[0] = (va.x - mu) * rstd * lg0.x + lb0.x;
            hn[1] = (va.y - mu) * rstd * lg0.y + lb0.y;
            hn[2] = (va.z - mu) * rstd * lg0.z + lb0.z;
            hn[3] = (va.w - mu) * rstd * lg0.w + lb0.w;
            hn[4] = (vb.x - mu) * rstd * lg1.x + lb1.x;
            hn[5] = (vb.y - mu) * rstd * lg1.y + lb1.y;
            hn[6] = (vb.z - mu) * rstd * lg1.z + lb1.z;
            hn[7] = (vb.w - mu) * rstd * lg1.w + lb1.w;
            #pragma unroll
            for (int fl = 0; fl < 8; ++fl) rbf4(hn[fl], bas[fl]);
            slv[0] = va.x / (1.0f + __expf(-va.x));
            slv[1] = va.y / (1.0f + __expf(-va.y));
            slv[2] = va.z / (1.0f + __expf(-va.z));
            slv[3] = va.w / (1.0f + __expf(-va.w));
            slv[4] = vb.x / (1.0f + __expf(-vb.x));
            slv[5] = vb.y / (1.0f + __expf(-vb.y));
            slv[6] = vb.z / (1.0f + __expf(-vb.z));
            slv[7] = vb.w / (1.0f + __expf(-vb.w));
        }
        const short* bp = wtf + (pl * 5) * OT * 512 + lane * 8;
        #pragma unroll
        for (int c = 0; c < 5; ++c) {
            AU a;
            #pragma unroll
            for (int i = 0; i < 4; ++i) {
                int s0i = c * 8 + 2 * i, s1i = s0i + 1;   // compile-time slot ids
                float vlo = (s0i % 5 == 4) ? slv[s0i / 5] : bas[s0i / 5][s0i % 5];
                float vhi = (s1i % 5 == 4) ? slv[s1i / 5] : bas[s1i / 5][s1i % 5];
                a.u[i] = pk2bf(vlo, vhi);
            }
            #pragma unroll
            for (int ot = 0; ot < OT; ++ot) {
                short8 b = *(const short8*)(bp + (c * OT + ot) * 512);
                acc[ot] = __builtin_amdgcn_mfma_f32_16x16x32_bf16(a.s, b, acc[ot], 0, 0, 0);
            }
        }
    }

    // ---- epilogue: bf16 write, C/D: col=lane&15, row=(lane>>4)*4+reg
    const int nrow0 = blockIdx.x * 64 + wv * 16 + q * 4;
    #pragma unroll
    for (int ot = 0; ot < OT; ++ot) {
        int o = ot * 16 + m;
        if (o < DO) {
            float cb = sb[o] + bb[o];
            #pragma unroll
            for (int r = 0; r < 4; ++r) {
                int nr = nrow0 + r;
                if (nr < NN) out[nr * DO + o] = f2bf(acc[ot][r] + cb);
            }
        }
    }
}

// ---------------------------------------------------------------- FastKAN layer (LDS-staged, conv2)
template<int D, int DO, int OT, int KKC, int NODES, int WPE, bool RAWLDS, bool BN>
__global__ __launch_bounds__(NODES * 4, WPE) void fkan_reg(
    const float* __restrict__ s0, const float* __restrict__ s1, const float* __restrict__ s2,
    const float2* __restrict__ bnp,
    const float* __restrict__ ln_g, const float* __restrict__ ln_b,
    const short* __restrict__ wtf, const float* __restrict__ sb, const float* __restrict__ bb,
    short* __restrict__ out)
{
    constexpr int BW   = D / 4;        // features per g4-block (per thread)
    constexpr int GBS  = BW + 1;       // g4-block stride (u32)
    constexpr int RS   = 4 * GBS + 1;  // node row stride (u32)
    constexpr int PPC  = KKC / 5;      // periods (8 feat each)
    constexpr int NV   = RAWLDS ? 1 : (BW / 4);
    __shared__ unsigned pkL[NODES * RS];

    const int tid = threadIdx.x;
    const int anode = tid >> 2, q = tid & 3;
    const int gnode = blockIdx.x * NODES + anode;
    const int snode = (gnode < NN) ? gnode : (NN - 1);
    unsigned* prow = &pkL[anode * RS + q * GBS];

    float mu, rstd;
    float4 va[NV];
    {
        float sum = 0.f, sq = 0.f;
        #pragma unroll
        for (int i4 = 0; i4 < BW / 4; ++i4) {
            int f = q * BW + i4 * 4;
            const float* src = (D == 128) ? s0 : ((f < 128) ? s0 : (f < 256) ? s1 : s2);
            float4 v = *(const float4*)&src[snode * 128 + (f & 127)];
            if constexpr (BN) {
                float4 ba = *(const float4*)&bnp[f];       // sc0,sh0,sc1,sh1
                float4 bc = *(const float4*)&bnp[f + 2];   // sc2,sh2,sc3,sh3
                v.x = fmaf(v.x, ba.x, ba.y);
                v.y = fmaf(v.y, ba.z, ba.w);
                v.z = fmaf(v.z, bc.x, bc.y);
                v.w = fmaf(v.w, bc.z, bc.w);
            }
            if constexpr (RAWLDS) {
                prow[i4 * 4 + 0] = __builtin_bit_cast(unsigned, v.x);
                prow[i4 * 4 + 1] = __builtin_bit_cast(unsigned, v.y);
                prow[i4 * 4 + 2] = __builtin_bit_cast(unsigned, v.z);
                prow[i4 * 4 + 3] = __builtin_bit_cast(unsigned, v.w);
            } else {
                va[i4] = v;
            }
            sum += (v.x + v.y) + (v.z + v.w);
            sq  += (v.x * v.x + v.y * v.y) + (v.z * v.z + v.w * v.w);
        }
        sum += __shfl_xor(sum, 1); sum += __shfl_xor(sum, 2);
        sq  += __shfl_xor(sq, 1);  sq  += __shfl_xor(sq, 2);
        mu   = sum * (1.0f / D);
        rstd = rsqrtf(sq * (1.0f / D) - mu * mu + LN_EPS);
    }

    // ---- phase A2: LN + silu, pk into LDS (in place for RAWLDS), 4 features/iter
    #pragma unroll
    for (int i4 = 0; i4 < BW / 4; ++i4) {
        int f = q * BW + i4 * 4;
        float4 v;
        if constexpr (RAWLDS) {
            v.x = __builtin_bit_cast(float, prow[i4 * 4 + 0]);
            v.y = __builtin_bit_cast(float, prow[i4 * 4 + 1]);
            v.z = __builtin_bit_cast(float, prow[i4 * 4 + 2]);
            v.w = __builtin_bit_cast(float, prow[i4 * 4 + 3]);
        } else {
            v = va[i4];
        }
        float4 lg = *(const float4*)&ln_g[f];
        float4 lb = *(const float4*)&ln_b[f];
        float hn[4], sl[4];
        hn[0] = (v.x - mu) * rstd * lg.x + lb.x;
        hn[1] = (v.y - mu) * rstd * lg.y + lb.y;
        hn[2] = (v.z - mu) * rstd * lg.z + lb.z;
        hn[3] = (v.w - mu) * rstd * lg.w + lb.w;
        sl[0] = v.x / (1.0f + __expf(-v.x));
        sl[1] = v.y / (1.0f + __expf(-v.y));
        sl[2] = v.z / (1.0f + __expf(-v.z));
        sl[3] = v.w / (1.0f + __expf(-v.w));
        #pragma unroll
        for (int k = 0; k < 4; ++k)
            prow[i4 * 4 + k] = pk2bf(sl[k], hn[k]);    // lo=silu, hi=hn
    }
    __syncthreads();

    // ---- phase 2: register-A MFMA (8 LDS reads/period, 2-exp RBF, perm pack)
    const int wv = tid >> 6, lane = tid & 63;
    const int m = lane & 15, g4 = lane >> 4;
    const unsigned* pkb = &pkL[(wv * 16 + m) * RS + g4 * GBS];

    f32x4 acc[OT];
    #pragma unroll
    for (int ot = 0; ot < OT; ++ot) acc[ot] = f32x4{0.f, 0.f, 0.f, 0.f};

    union AU { unsigned u[4]; short8 s; };

    for (int pl = 0; pl < PPC; ++pl) {             // 5 kk = 40 slots = 8 features
        const unsigned* pp = pkb + pl * 8;
        float bas[8][4], slv[8];
        #pragma unroll
        for (int fl = 0; fl < 8; ++fl) {
            unsigned pv = pp[fl];
            float hn = __builtin_bit_cast(float, pv & 0xffff0000u);
            slv[fl]  = __builtin_bit_cast(float, pv << 16);
            rbf4(hn, bas[fl]);
        }
        const short* bp = wtf + (pl * 5) * OT * 512 + lane * 8;
        #pragma unroll
        for (int c = 0; c < 5; ++c) {
            AU a;
            #pragma unroll
            for (int i = 0; i < 4; ++i) {
                int s0i = c * 8 + 2 * i, s1i = s0i + 1;   // compile-time slot ids
                float vlo = (s0i % 5 == 4) ? slv[s0i / 5] : bas[s0i / 5][s0i % 5];
                float vhi = (s1i % 5 == 4) ? slv[s1i / 5] : bas[s1i / 5][s1i % 5];
                a.u[i] = pk2bf(vlo, vhi);
            }
            #pragma unroll
            for (int ot = 0; ot < OT; ++ot) {
                short8 b = *(const short8*)(bp + (c * OT + ot) * 512);
                acc[ot] = __builtin_amdgcn_mfma_f32_16x16x32_bf16(a.s, b, acc[ot], 0, 0, 0);
            }
        }
    }

    // ---- epilogue: bf16 write, C/D: col=lane&15, row=(lane>>4)*4+reg
    const int nrow0 = blockIdx.x * NODES + wv * 16 + g4 * 4;
    #pragma unroll
    for (int ot = 0; ot < OT; ++ot) {
        int o = ot * 16 + m;
        if (o < DO) {
            float cb = sb[o] + bb[o];
            #pragma unroll
            for (int r = 0; r < 4; ++r) {
                int nr = nrow0 + r;
                if (nr < NN) out[nr * DO + o] = f2bf(acc[ot][r] + cb);
            }
        }
    }
}

// ---------------------------------------------------------------- CSR gather (bf16 rows)
template<int DO>
__global__ __launch_bounds__(64) void agg_gather_bf16(
    const int* __restrict__ off, const int* __restrict__ rows,
    const float* __restrict__ dis, const short* __restrict__ hwb,
    const float* __restrict__ bias, float* __restrict__ out)
{
    constexpr int ACT = DO / 2;        // active compute lanes
    const int n   = blockIdx.x;
    const int tid = threadIdx.x;
    __shared__ int   srow[64];
    __shared__ float swgt[64];

    const int e0 = off[n], e1 = off[n + 1];
    const float dn = dis[n];
    float ax = 0.f, ay = 0.f;
    if (tid < ACT) {
        unsigned p = *(const unsigned*)&hwb[n * DO + 2 * tid];
        float2 v = bf2x2(p);
        ax = dn * dn * v.x + bias[2 * tid];
        ay = dn * dn * v.y + bias[2 * tid + 1];
    }

    for (int t0 = e0; t0 < e1; t0 += 64) {
        const int nt = min(64, e1 - t0);
        if (tid < nt) {
            int r = rows[t0 + tid];
            srow[tid] = r;
            swgt[tid] = dn * dis[r];
        }
        __syncthreads();
        if (tid < ACT) {
            #pragma unroll 4
            for (int j = 0; j < nt; ++j) {
                unsigned p = *(const unsigned*)&hwb[srow[j] * DO + 2 * tid];
                float2 v = bf2x2(p);
                float w = swgt[j];
                ax += w * v.x;
                ay += w * v.y;
            }
        }
        __syncthreads();
    }
    if (tid < ACT) {
        out[n * DO + 2 * tid]     = ax;
        out[n * DO + 2 * tid + 1] = ay;
    }
}

// ---------------------------------------------------------------- batchnorm stats
__global__ void bn_stats(const float* __restrict__ h, float* __restrict__ stats)
{
    __shared__ float s1[256], s2[256];
    int c = threadIdx.x & 127;
    int half = threadIdx.x >> 7;
    float sum = 0.f, sq = 0.f;
    for (int n = blockIdx.x * 2 + half; n < NN; n += 512) {
        float v = h[n * 128 + c];
        sum += v; sq += v * v;
    }
    s1[threadIdx.x] = sum; s2[threadIdx.x] = sq;
    __syncthreads();
    if (half == 0) {
        s1[c] += s1[c + 128]; s2[c] += s2[c + 128];
        atomicAdd(&stats[c],        s1[c]);
        atomicAdd(&stats[c + 128],  s2[c]);
    }
}

// ---------------------------------------------------------------- launcher
extern "C" void kernel_launch(void* const* d_in, const int* in_sizes, int n_in,
                              void* d_out, int out_size, void* d_ws, size_t ws_size,
                              hipStream_t stream)
{
    auto F = [&](int i) { return (const float*)d_in[i]; };
    const float* x  = F(0);
    const int*   ei = (const int*)d_in[1];
    const float* bn_g = F(23);
    const float* bn_b = F(24);
    // per-conv params: base = 2 + 7*i : ln_g, ln_b, sw, sb, bw, bb, bias

    // ---- workspace layout
    short*  wtf0 = (short*)d_ws;                // 81920 shorts
    short*  wtf1 = wtf0 + 81920;                // 81920
    short*  wtf2 = wtf1 + 81920;                // 92160
    short*  hwb  = wtf2 + 92160;                // NN*128 bf16 (NN*40 for conv2)
    float*  dis  = (float*)(hwb + 6400000);     // NN
    float2* bnp  = (float2*)(dis + 50000);      // 384: [id | conv0-bn | conv1-bn]
    float*  h1   = (float*)(bnp + 384);         // NN*128 (raw agg)
    float*  h2   = h1 + 6400000;
    float*  stats = h2 + 6400000;               // 256
    int*    degi = (int*)(stats + 256);         // NN
    int*    off  = degi + 50000;                // NN+1
    int*    cur  = off + 50001;                 // NN
    int*    rows = cur + 50000;                 // NE
    int*    histo = rows + NE;                  // 8*NB1 = 6256
    int*    partials = histo + NBKT * NB1;      // NSB+1 = 197
    int*    pcnt = partials + NSB + 1;          // 8*8*6250 = 400000
    uint2*  staging = (uint2*)h1;               // 12.8 MB, dead until conv0 output
    float*  outf = (float*)d_out;

    // ---- CSR build: hist -> scan2 -> part -> degree (LDS hist) -> scans -> scatter
    (void)hipMemsetAsync(cur, 0, 50000 * sizeof(int), stream);
    csr_hist<<<NB1, 256, 0, stream>>>(ei + NE, histo);
    csr_scan2<<<1, 256, 0, stream>>>(histo);
    csr_part<<<NB1, 256, 0, stream>>>(ei, histo, staging);
    deg_part<<<NBKT * PPB, 256, 0, stream>>>(staging, histo, pcnt);
    deg_reduce<<<NSB, 256, 0, stream>>>(pcnt, degi);
    dis_kernel<<<(NN + 255) / 256, 256, 0, stream>>>(degi, dis);
    scan_p1<<<NSB, 256, 0, stream>>>(degi, off, partials);
    scan_p2<<<1, 256, 0, stream>>>(partials);
    scan_p3<<<NSB, 256, 0, stream>>>(off, partials);
    csr_scatter<128><<<128 * NBKT, 256, 0, stream>>>(staging, off, cur, rows);

    // ---- pack B fragments (bf16), BN identity section
    pack_frag<<<(81920 + 255) / 256, 256, 0, stream>>>(F(4),  F(6),  wtf0, 128, 8, 128, 81920);
    pack_frag<<<(81920 + 255) / 256, 256, 0, stream>>>(F(11), F(13), wtf1, 128, 8, 128, 81920);
    pack_frag<<<(92160 + 255) / 256, 256, 0, stream>>>(F(18), F(20), wtf2, 384, 3, 40,  92160);
    bn_id<<<1, 128, 0, stream>>>(bnp);

    const int gridN64 = (NN + 63) / 64;         // 782
    const int gridN16 = (NN + 15) / 16;         // 3125

    // ---- conv0: x -> h1 (register-direct fkan, no LDS)
    fkan_rd<128, 8, 20, false><<<gridN64, 256, 0, stream>>>(x,
        nullptr, F(2), F(3), wtf0, F(5), F(7), hwb);
    agg_gather_bf16<128><<<NN, 64, 0, stream>>>(off, rows, dis, hwb, F(8), h1);
    (void)hipMemsetAsync(stats, 0, 256 * sizeof(float), stream);
    bn_stats<<<256, 256, 0, stream>>>(h1, stats);
    bn_final<<<1, 128, 0, stream>>>(stats, bn_g, bn_b, bnp + 128);

    // ---- conv1: h1 -> h2 (register-direct fkan, BN fused)
    fkan_rd<128, 8, 20, true><<<gridN64, 256, 0, stream>>>(h1,
        bnp + 128, F(9), F(10), wtf1, F(12), F(14), hwb);
    agg_gather_bf16<128><<<NN, 64, 0, stream>>>(off, rows, dis, hwb, F(15), h2);
    (void)hipMemsetAsync(stats, 0, 256 * sizeof(float), stream);
    bn_stats<<<256, 256, 0, stream>>>(h2, stats);
    bn_final<<<1, 128, 0, stream>>>(stats, bn_g, bn_b, bnp + 256);

    // ---- conv2: [x|h1|h2] -> d_out (raw-LDS staging, 16-node single-wave blocks)
    fkan_reg<384, 40, 3, 60, 16, 2, true, true><<<gridN16, 64, 0, stream>>>(x, h1, h2,
        bnp, F(16), F(17), wtf2, F(19), F(21), hwb);
    agg_gather_bf16<40><<<NN, 64, 0, stream>>>(off, rows, dis, hwb, F(22), outf);
}